// Round 17
// baseline (229.486 us; speedup 1.0000x reference)
//
#include <hip/hip_runtime.h>

typedef _Float16 f16;
typedef _Float16 f16x4 __attribute__((ext_vector_type(4)));
typedef _Float16 f16x8 __attribute__((ext_vector_type(8)));
typedef float f32x4 __attribute__((ext_vector_type(4)));

#define TPB  768           // 12 waves (3 per SIMD)
#define TPBF 576           // fallback kernel
#define NWIN 16            // windows per block
#define XS   200           // Xh row stride (halves): 400B = 25x16B
#define WSS  200           // fallback Wh row stride
#define QS   40            // Qh/Kh/AOh/Wp row stride: 80B = 5x16B
#define VS   264           // Vt2 row stride: 528B = 33x16B

// ws layout:
//   wsWqf [6 heads][6 ct][6 kk][64 lane] x f16x8 (fragment-direct) = 221184 B
//   wsWp  [6 heads][192 r][40 c] f16 (padded LDS image for DMA)    = 92160 B
#define WSQF_HALVES 110592
#define WSP_HALVES_PER_HEAD (192 * 40)     // 7680
#define WS_NEEDED (221184 + 92160)

__device__ __forceinline__ void gload16(const void* g, void* l) {
    __builtin_amdgcn_global_load_lds(
        (const __attribute__((address_space(1))) unsigned int*)g,
        (__attribute__((address_space(3))) unsigned int*)l, 16, 0, 0);
}

// ---- pre-kernel: Wqkv -> per-lane fragment order; Wproj -> padded LDS image ----
__global__ __launch_bounds__(512) void conv_w(
    const float* __restrict__ Wqkv, const float* __restrict__ Wproj,
    f16* __restrict__ wsWqf, f16* __restrict__ wsWp)
{
    int idx = blockIdx.x * 512 + threadIdx.x;   // 288 * 512 = 147456 exact
    if (idx < WSQF_HALVES) {
        int h    = idx / 18432;
        int rem  = idx % 18432;
        int ct   = rem / 3072;
        int rem2 = rem % 3072;
        int kk   = rem2 / 512;
        int rem3 = rem2 % 512;
        int lane = rem3 / 8;
        int e    = rem3 % 8;
        int r    = 16 * ct + (lane & 15);
        int grow = (r >> 5) * 192 + h * 32 + (r & 31);
        int col  = kk * 32 + (lane >> 4) * 8 + e;
        wsWqf[idx] = (f16)Wqkv[grow * 192 + col];
    } else {
        int j = idx - WSQF_HALVES;               // < 36864 = 6*192*32
        int h = j / (192 * 32), rem = j % (192 * 32);
        int r = rem / 32, c = rem % 32;
        wsWp[(h * 192 + r) * 40 + c] = (f16)Wproj[r * 192 + h * 32 + c];
    }
}

__global__ __launch_bounds__(TPB) void lsa_mfma16(
    const float* __restrict__ x, const f16* __restrict__ wsWqf,
    const f16* __restrict__ wsWp, const float* __restrict__ bproj,
    float* __restrict__ out)
{
    // LDS: 57600 + 11520 + 11520 + 16896 + 11520 + 15360 = 124416 B
    __shared__ __attribute__((aligned(16))) f16 Xh[144 * XS];
    __shared__ __attribute__((aligned(16))) f16 Qh[144 * QS];
    __shared__ __attribute__((aligned(16))) f16 Kh[144 * QS];
    __shared__ __attribute__((aligned(16))) f16 Vt2[32 * VS];
    __shared__ __attribute__((aligned(16))) f16 AOh[144 * QS];
    __shared__ __attribute__((aligned(16))) f16 Wp[192 * QS];

    const int tid  = threadIdx.x;
    const int lane = tid & 63;
    const int w    = tid >> 6;      // wave 0..11
    const int ci   = w % 3;         // QKV ct-pair {ci, ci+3}
    const int tg   = w / 3;         // QKV token-group: tiles {tg, tg+4, tg+8(<9)}
    const int l15  = lane & 15;
    const int lg   = lane >> 4;     // 0..3

    // ---- geometry: 16 windows per block ----
    const int  bb    = blockIdx.x / 768;
    const int  gbase = (blockIdx.x % 768) * NWIN;
    const long rb0   = (long)bb * 110592 + (long)(gbase / 96) * 864 + (long)(gbase % 96) * 3;

    const f16x8* wqf = (const f16x8*)wsWqf;   // ((h*6+ct)*6+kk)*64 + lane

    // ---- prologue: X -> LDS fp16; zero Vt2 ----
    for (int i = 0; i < 9; ++i) {                // 9 exact iters (6912 = 9*768)
        int idx = i * TPB + tid;
        int t = idx / 48, c4 = idx % 48;
        int wi = t / 9, q = t - 9 * wi;
        long grow = rb0 + wi * 3 + (q / 3) * 288 + (q % 3);
        float4 xv = ((const float4*)x)[grow * 48 + c4];
        union { f16 h[4]; ushort4 u; } tmp;
        tmp.h[0] = (f16)xv.x; tmp.h[1] = (f16)xv.y; tmp.h[2] = (f16)xv.z; tmp.h[3] = (f16)xv.w;
        *(ushort4*)&Xh[t * XS + c4 * 4] = tmp.u;
    }
    {
        int4 z = {0, 0, 0, 0};
        for (int i2 = tid; i2 < (32 * VS * 2) / 16; i2 += TPB) ((int4*)Vt2)[i2] = z;
    }

    f32x4 pacc[9];
    #pragma unroll
    for (int a = 0; a < 9; ++a) pacc[a] = (f32x4){0.f, 0.f, 0.f, 0.f};

    __syncthreads();   // P: Xh + Vt2-zero ready

    for (int h = 0; h < 6; ++h) {
        // ---- phase A: QKV GEMM (A = W fragments direct from L2, B = X from LDS) ----
        f32x4 qacc[2][3];
        #pragma unroll
        for (int c = 0; c < 2; ++c)
            #pragma unroll
            for (int t = 0; t < 3; ++t)
                qacc[c][t] = (f32x4){0.f, 0.f, 0.f, 0.f};
        #pragma unroll
        for (int kk = 0; kk < 6; ++kk) {
            f16x8 af[2];
            af[0] = wqf[((h * 6 + ci    ) * 6 + kk) * 64 + lane];
            af[1] = wqf[((h * 6 + ci + 3) * 6 + kk) * 64 + lane];
            #pragma unroll
            for (int t = 0; t < 3; ++t) {
                int tt = tg + 4 * t;
                if (tt < 9) {
                    f16x8 bf = *(const f16x8*)&Xh[(16 * tt + l15) * XS + kk * 32 + lg * 8];
                    qacc[0][t] = __builtin_amdgcn_mfma_f32_16x16x32_f16(af[0], bf, qacc[0][t], 0, 0, 0);
                    qacc[1][t] = __builtin_amdgcn_mfma_f32_16x16x32_f16(af[1], bf, qacc[1][t], 0, 0, 0);
                }
            }
        }
        // scatter: lane holds channels (ct*16 + 4lg..+3) of token (16*tt + l15)
        #pragma unroll
        for (int c = 0; c < 2; ++c) {
            const int ct = ci + 3 * c;            // 0..5 wave-uniform
            #pragma unroll
            for (int t = 0; t < 3; ++t) {
                int tt = tg + 4 * t;
                if (tt < 9) {
                    const int token = 16 * tt + l15;
                    f16x4 ph;
                    ph[0] = (f16)qacc[c][t][0]; ph[1] = (f16)qacc[c][t][1];
                    ph[2] = (f16)qacc[c][t][2]; ph[3] = (f16)qacc[c][t][3];
                    if (ct < 2) {
                        *(f16x4*)&Qh[token * QS + ct * 16 + 4 * lg] = ph;
                    } else if (ct < 4) {
                        *(f16x4*)&Kh[token * QS + (ct - 2) * 16 + 4 * lg] = ph;
                    } else {
                        const int d0 = (ct - 4) * 16 + 4 * lg;
                        int wi = token / 9, qq = token - 9 * wi;
                        #pragma unroll
                        for (int r = 0; r < 4; ++r)
                            Vt2[(d0 + r) * VS + 16 * wi + qq] = ph[r];
                    }
                }
            }
        }
        __syncthreads();   // B: Q/K/V ready

        // ---- phase B: DMA Wp(h) || attention ----
        for (int l = tid; l < 960; l += TPB)      // 15360 B = 960 x 16B
            gload16(wsWp + h * WSP_HALVES_PER_HEAD + l * 8, (char*)Wp + l * 16);

        for (int wi = w; wi < NWIN; wi += 12) {
            int krow = 9 * wi + l15;
            krow = krow > 143 ? 143 : krow;        // clamp pad lanes (results discarded)
            f16x8 ak = *(const f16x8*)&Kh[krow * QS + lg * 8];
            f16x8 aq = *(const f16x8*)&Qh[krow * QS + lg * 8];
            f32x4 s = (f32x4){0.f, 0.f, 0.f, 0.f};
            s = __builtin_amdgcn_mfma_f32_16x16x32_f16(ak, aq, s, 0, 0, 0);
            // lane holds S[k = 4lg+r][q = l15]
            float lgt[4];
            float mx = -1e30f;
            #pragma unroll
            for (int r = 0; r < 4; ++r) {
                int kx = 4 * lg + r;
                lgt[r] = (kx < 9) ? s[r] * 0.17677669529663687f : -1e30f;
                mx = fmaxf(mx, lgt[r]);
            }
            mx = fmaxf(mx, __shfl_xor(mx, 16));
            mx = fmaxf(mx, __shfl_xor(mx, 32));
            float e[4], sum = 0.f;
            #pragma unroll
            for (int r = 0; r < 4; ++r) {
                int kx = 4 * lg + r;
                e[r] = (kx < 9) ? __expf(lgt[r] - mx) : 0.f;
                sum += e[r];
            }
            sum += __shfl_xor(sum, 16);
            sum += __shfl_xor(sum, 32);
            float inv = 1.0f / sum;
            f16x4 p;
            p[0] = (f16)(e[0] * inv); p[1] = (f16)(e[1] * inv);
            p[2] = (f16)(e[2] * inv); p[3] = (f16)(e[3] * inv);
            // p IS the B-frag of 16x16x16: B[row=q=l15][k=4lg..+3]
            #pragma unroll
            for (int dt = 0; dt < 2; ++dt) {
                f16x4 av = *(const f16x4*)&Vt2[(dt * 16 + l15) * VS + 16 * wi + 4 * lg];
                f32x4 o = (f32x4){0.f, 0.f, 0.f, 0.f};
                o = __builtin_amdgcn_mfma_f32_16x16x16f16(av, p, o, 0, 0, 0);
                // D: row(4lg+r) = d-in-tile, col(l15) = q
                if (l15 < 9) {
                    f16x4 oh;
                    oh[0] = (f16)o[0]; oh[1] = (f16)o[1]; oh[2] = (f16)o[2]; oh[3] = (f16)o[3];
                    *(f16x4*)&AOh[(9 * wi + l15) * QS + dt * 16 + 4 * lg] = oh;
                }
            }
        }
        __syncthreads();   // C: AOh + Wp ready (vmcnt drained by barrier)

        // ---- phase A-tail: proj partial — wave w owns output N-tile w ----
        {
            f16x8 bw = *(const f16x8*)&Wp[(16 * w + l15) * QS + lg * 8];
            #pragma unroll
            for (int a = 0; a < 9; ++a) {
                f16x8 aof = *(const f16x8*)&AOh[(16 * a + l15) * QS + lg * 8];
                pacc[a] = __builtin_amdgcn_mfma_f32_16x16x32_f16(aof, bw, pacc[a], 0, 0, 0);
            }
        }
        // no trailing barrier: next head's barrier B fences AOh/Wp rewrites
    }

    // ---- epilogue: pacc + bias -> out (D row = token, D col = channel 16w+l15) ----
    const float bv = bproj[16 * w + l15];
    #pragma unroll
    for (int a = 0; a < 9; ++a) {
        #pragma unroll
        for (int r = 0; r < 4; ++r) {
            int t = 16 * a + lg * 4 + r;
            int wi = t / 9, q = t - 9 * wi;
            long grow = rb0 + wi * 3 + (q / 3) * 288 + (q % 3);
            out[grow * 192 + 16 * w + l15] = pacc[a][r] + bv;
        }
    }
}

// ---- fallback: R8 kernel verbatim (used if ws_size is too small) ----
__global__ __launch_bounds__(TPBF) void lsa_mfma7(
    const float* __restrict__ x, const float* __restrict__ Wqkv,
    const float* __restrict__ Wproj, const float* __restrict__ bproj,
    float* __restrict__ out)
{
    __shared__ f16 Xh[144 * XS];
    __shared__ f16 Wh[96 * WSS];
    __shared__ f16 Qh[144 * QS];
    __shared__ f16 Kh[144 * QS];
    __shared__ f16 Vt2[32 * VS];
    __shared__ f16 AOh[144 * QS];
    __shared__ f16 Wp[192 * QS];

    const int tid  = threadIdx.x;
    const int lane = tid & 63;
    const int w    = tid >> 6;
    const int ci   = w / 3;
    const int ti   = w % 3;
    const int l15  = lane & 15;
    const int lg   = lane >> 4;

    const int  bb    = blockIdx.x / 768;
    const int  gbase = (blockIdx.x % 768) * NWIN;
    const long rb0   = (long)bb * 110592 + (long)(gbase / 96) * 864 + (long)(gbase % 96) * 3;

    const float4* Wq4 = (const float4*)Wqkv;
    const float4* Wp4 = (const float4*)Wproj;

    for (int idx = tid; idx < 144 * 48; idx += TPBF) {
        int t = idx / 48, c4 = idx % 48;
        int wi = t / 9, q = t - 9 * wi;
        long grow = rb0 + wi * 3 + (q / 3) * 288 + (q % 3);
        float4 xv = ((const float4*)x)[grow * 48 + c4];
        union { f16 h[4]; ushort4 u; } tmp;
        tmp.h[0] = (f16)xv.x; tmp.h[1] = (f16)xv.y; tmp.h[2] = (f16)xv.z; tmp.h[3] = (f16)xv.w;
        *(ushort4*)&Xh[t * XS + c4 * 4] = tmp.u;
    }
    {
        int4 z = {0, 0, 0, 0};
        for (int i2 = tid; i2 < (32 * VS * 2) / 16; i2 += TPBF) ((int4*)Vt2)[i2] = z;
    }
    #pragma unroll
    for (int i = 0; i < 8; ++i) {
        int l = i * TPBF + tid;
        int r = l / 48, c4 = l % 48;
        float4 wv = Wq4[((r >> 5) * 192 + (r & 31)) * 48 + c4];
        union { f16 h4[4]; ushort4 u; } t;
        t.h4[0] = (f16)wv.x; t.h4[1] = (f16)wv.y; t.h4[2] = (f16)wv.z; t.h4[3] = (f16)wv.w;
        *(ushort4*)&Wh[r * WSS + c4 * 4] = t.u;
    }

    f32x4 pacc[3][4];
    #pragma unroll
    for (int a = 0; a < 3; ++a)
        #pragma unroll
        for (int bq = 0; bq < 4; ++bq)
            pacc[a][bq] = (f32x4){0.f, 0.f, 0.f, 0.f};

    __syncthreads();

    for (int h = 0; h < 6; ++h) {
        f32x4 qacc[2][3];
        #pragma unroll
        for (int c = 0; c < 2; ++c)
            #pragma unroll
            for (int t = 0; t < 3; ++t)
                qacc[c][t] = (f32x4){0.f, 0.f, 0.f, 0.f};
        #pragma unroll
        for (int kk = 0; kk < 6; ++kk) {
            f16x8 af[2], bf[3];
            #pragma unroll
            for (int c = 0; c < 2; ++c)
                af[c] = *(const f16x8*)&Wh[(16 * (ci + 3 * c) + l15) * WSS + kk * 32 + lg * 8];
            #pragma unroll
            for (int t = 0; t < 3; ++t)
                bf[t] = *(const f16x8*)&Xh[(16 * (ti + 3 * t) + l15) * XS + kk * 32 + lg * 8];
            #pragma unroll
            for (int c = 0; c < 2; ++c)
                #pragma unroll
                for (int t = 0; t < 3; ++t)
                    qacc[c][t] = __builtin_amdgcn_mfma_f32_16x16x32_f16(af[c], bf[t], qacc[c][t], 0, 0, 0);
        }
        #pragma unroll
        for (int c = 0; c < 2; ++c) {
            const int ct = ci + 3 * c;
            #pragma unroll
            for (int t = 0; t < 3; ++t) {
                const int token = 16 * (ti + 3 * t) + l15;
                f16x4 ph;
                ph[0] = (f16)qacc[c][t][0]; ph[1] = (f16)qacc[c][t][1];
                ph[2] = (f16)qacc[c][t][2]; ph[3] = (f16)qacc[c][t][3];
                if (ct < 2) {
                    *(f16x4*)&Qh[token * QS + ct * 16 + 4 * lg] = ph;
                } else if (ct < 4) {
                    *(f16x4*)&Kh[token * QS + (ct - 2) * 16 + 4 * lg] = ph;
                } else {
                    const int d0 = (ct - 4) * 16 + 4 * lg;
                    int wi = token / 9, qq = token - 9 * wi;
                    #pragma unroll
                    for (int r = 0; r < 4; ++r)
                        Vt2[(d0 + r) * VS + 16 * wi + qq] = ph[r];
                }
            }
        }
        __syncthreads();

        float4 wpv[3];
        if (tid < 512) {
            #pragma unroll
            for (int i = 0; i < 3; ++i) {
                int l = i * 512 + tid;
                int r = l / 8, c4 = l % 8;
                wpv[i] = Wp4[r * 48 + h * 8 + c4];
            }
        }
        if (h < 5) {
            #pragma unroll
            for (int i = 0; i < 8; ++i) {
                int l = i * TPBF + tid;
                int r = l / 48, c4 = l % 48;
                float4 wv = Wq4[((r >> 5) * 192 + (h + 1) * 32 + (r & 31)) * 48 + c4];
                union { f16 h4[4]; ushort4 u; } t;
                t.h4[0] = (f16)wv.x; t.h4[1] = (f16)wv.y; t.h4[2] = (f16)wv.z; t.h4[3] = (f16)wv.w;
                *(ushort4*)&Wh[r * WSS + c4 * 4] = t.u;
            }
        }
        for (int wi = w; wi < NWIN; wi += 9) {
            int krow = 9 * wi + l15;
            krow = krow > 143 ? 143 : krow;
            f16x8 ak = *(const f16x8*)&Kh[krow * QS + lg * 8];
            f16x8 aq = *(const f16x8*)&Qh[krow * QS + lg * 8];
            f32x4 s = (f32x4){0.f, 0.f, 0.f, 0.f};
            s = __builtin_amdgcn_mfma_f32_16x16x32_f16(ak, aq, s, 0, 0, 0);
            float lgt[4];
            float mx = -1e30f;
            #pragma unroll
            for (int r = 0; r < 4; ++r) {
                int kx = 4 * lg + r;
                lgt[r] = (kx < 9) ? s[r] * 0.17677669529663687f : -1e30f;
                mx = fmaxf(mx, lgt[r]);
            }
            mx = fmaxf(mx, __shfl_xor(mx, 16));
            mx = fmaxf(mx, __shfl_xor(mx, 32));
            float e[4], sum = 0.f;
            #pragma unroll
            for (int r = 0; r < 4; ++r) {
                int kx = 4 * lg + r;
                e[r] = (kx < 9) ? __expf(lgt[r] - mx) : 0.f;
                sum += e[r];
            }
            sum += __shfl_xor(sum, 16);
            sum += __shfl_xor(sum, 32);
            float inv = 1.0f / sum;
            f16x4 p;
            p[0] = (f16)(e[0] * inv); p[1] = (f16)(e[1] * inv);
            p[2] = (f16)(e[2] * inv); p[3] = (f16)(e[3] * inv);
            #pragma unroll
            for (int dt = 0; dt < 2; ++dt) {
                f16x4 av = *(const f16x4*)&Vt2[(dt * 16 + l15) * VS + 16 * wi + 4 * lg];
                f32x4 o = (f32x4){0.f, 0.f, 0.f, 0.f};
                o = __builtin_amdgcn_mfma_f32_16x16x16f16(av, p, o, 0, 0, 0);
                if (l15 < 9) {
                    f16x4 oh;
                    oh[0] = (f16)o[0]; oh[1] = (f16)o[1]; oh[2] = (f16)o[2]; oh[3] = (f16)o[3];
                    *(f16x4*)&AOh[(9 * wi + l15) * QS + dt * 16 + 4 * lg] = oh;
                }
            }
        }
        if (tid < 512) {
            #pragma unroll
            for (int i = 0; i < 3; ++i) {
                int l = i * 512 + tid;
                int r = l / 8, c4 = l % 8;
                union { f16 h4[4]; ushort4 u; } t;
                t.h4[0] = (f16)wpv[i].x; t.h4[1] = (f16)wpv[i].y;
                t.h4[2] = (f16)wpv[i].z; t.h4[3] = (f16)wpv[i].w;
                *(ushort4*)&Wp[r * QS + c4 * 4] = t.u;
            }
        }
        __syncthreads();

        {
            f16x8 aof[3];
            #pragma unroll
            for (int a = 0; a < 3; ++a)
                aof[a] = *(const f16x8*)&AOh[(16 * (3 * ci + a) + l15) * QS + lg * 8];
            #pragma unroll
            for (int bq = 0; bq < 4; ++bq) {
                f16x8 bw = *(const f16x8*)&Wp[(16 * (4 * ti + bq) + l15) * QS + lg * 8];
                #pragma unroll
                for (int a = 0; a < 3; ++a)
                    pacc[a][bq] = __builtin_amdgcn_mfma_f32_16x16x32_f16(aof[a], bw, pacc[a][bq], 0, 0, 0);
            }
        }
    }

    float bv[4];
    #pragma unroll
    for (int bq = 0; bq < 4; ++bq)
        bv[bq] = bproj[16 * (4 * ti + bq) + l15];
    #pragma unroll
    for (int a = 0; a < 3; ++a) {
        #pragma unroll
        for (int r = 0; r < 4; ++r) {
            int t = 16 * (3 * ci + a) + lg * 4 + r;
            int wi = t / 9, q = t - 9 * wi;
            long grow = rb0 + wi * 3 + (q / 3) * 288 + (q % 3);
            float* dst = out + grow * 192;
            #pragma unroll
            for (int bq = 0; bq < 4; ++bq)
                dst[16 * (4 * ti + bq) + l15] = pacc[a][bq][r] + bv[bq];
        }
    }
}

extern "C" void kernel_launch(void* const* d_in, const int* in_sizes, int n_in,
                              void* d_out, int out_size, void* d_ws, size_t ws_size,
                              hipStream_t stream) {
    const float* x     = (const float*)d_in[0];
    const float* Wqkv  = (const float*)d_in[1];
    const float* Wproj = (const float*)d_in[2];
    const float* bproj = (const float*)d_in[3];
    float* out = (float*)d_out;
    if (ws_size >= (size_t)WS_NEEDED && d_ws != nullptr) {
        f16* wsWqf = (f16*)d_ws;
        f16* wsWp  = (f16*)((char*)d_ws + 221184);
        conv_w<<<288, 512, 0, stream>>>(Wqkv, Wproj, wsWqf, wsWp);
        lsa_mfma16<<<1536, TPB, 0, stream>>>(x, wsWqf, wsWp, bproj, out);
    } else {
        lsa_mfma7<<<1536, TPBF, 0, stream>>>(x, Wqkv, Wproj, bproj, out);
    }
}

// Round 18
// 198.009 us; speedup vs baseline: 1.1590x; 1.1590x over previous
//
#include <hip/hip_runtime.h>

typedef _Float16 f16;
typedef _Float16 f16x4 __attribute__((ext_vector_type(4)));
typedef _Float16 f16x8 __attribute__((ext_vector_type(8)));
typedef float f32x4 __attribute__((ext_vector_type(4)));

#define TPB  768           // 12 waves (3 per SIMD)
#define TPBF 576           // fallback kernel
#define NWIN 16            // windows per block
#define XS   200           // Xh row stride (halves): 400B = 25x16B
#define WSS  200           // Wh row stride
#define QS   40            // Qh/Kh/AOh/Wp row stride: 80B = 5x16B
#define VS   264           // Vt2 row stride: 528B = 33x16B

// ws layout: wsWq [6][96][200] f16 = 230400 B, then wsWp [6][192][40] f16 = 92160 B
#define WSQ_HALVES_PER_HEAD (96 * 200)     // 19200
#define WSP_HALVES_PER_HEAD (192 * 40)     // 7680
#define WS_NEEDED (230400 + 92160)

__device__ __forceinline__ void gload16(const void* g, void* l) {
    __builtin_amdgcn_global_load_lds(
        (const __attribute__((address_space(1))) unsigned int*)g,
        (__attribute__((address_space(3))) unsigned int*)l, 16, 0, 0);
}

// ---- pre-kernel: convert weights to fp16 in the exact padded LDS image ----
__global__ __launch_bounds__(512) void conv_w(
    const float* __restrict__ Wqkv, const float* __restrict__ Wproj,
    f16* __restrict__ wsWq, f16* __restrict__ wsWp)
{
    int idx = blockIdx.x * 512 + threadIdx.x;   // 288 blocks * 512 = 147456 exact
    if (idx < 110592) {                          // 6*96*192
        int h = idx / (96 * 192), rem = idx % (96 * 192);
        int r = rem / 192, c = rem % 192;
        int grow = (r >> 5) * 192 + h * 32 + (r & 31);
        wsWq[(h * 96 + r) * 200 + c] = (f16)Wqkv[grow * 192 + c];
    } else {
        int j = idx - 110592;                    // 6*192*32
        int h = j / (192 * 32), rem = j % (192 * 32);
        int r = rem / 32, c = rem % 32;
        wsWp[(h * 192 + r) * 40 + c] = (f16)Wproj[r * 192 + h * 32 + c];
    }
}

__global__ __launch_bounds__(TPB) void lsa_mfma14(
    const float* __restrict__ x, const f16* __restrict__ wsWq,
    const f16* __restrict__ wsWp, const float* __restrict__ bproj,
    float* __restrict__ out)
{
    // LDS: 57600 + 38400 + 11520 + 11520 + 16896 + 11520 + 15360 = 162816 B
    __shared__ __attribute__((aligned(16))) f16 Xh[144 * XS];
    __shared__ __attribute__((aligned(16))) f16 Wh[96 * WSS];
    __shared__ __attribute__((aligned(16))) f16 Qh[144 * QS];
    __shared__ __attribute__((aligned(16))) f16 Kh[144 * QS];
    __shared__ __attribute__((aligned(16))) f16 Vt2[32 * VS];
    __shared__ __attribute__((aligned(16))) f16 AOh[144 * QS];
    __shared__ __attribute__((aligned(16))) f16 Wp[192 * QS];

    const int tid  = threadIdx.x;
    const int lane = tid & 63;
    const int w    = tid >> 6;      // wave 0..11
    const int ci   = w % 3;         // QKV ct-pair {ci, ci+3}
    const int tg   = w / 3;         // QKV token-group: tiles {tg, tg+4, tg+8(<9)}
    const int l15  = lane & 15;
    const int lg   = lane >> 4;     // 0..3

    // ---- geometry: 16 windows per block ----
    const int  bb    = blockIdx.x / 768;
    const int  gbase = (blockIdx.x % 768) * NWIN;
    const long rb0   = (long)bb * 110592 + (long)(gbase / 96) * 864 + (long)(gbase % 96) * 3;

    // ---- prologue: DMA Wh(0); X -> LDS fp16; zero Vt2 ----
    for (int l = tid; l < 2400; l += TPB)        // 38400 B = 2400 x 16B
        gload16(wsWq + l * 8, (char*)Wh + l * 16);
    for (int i = 0; i < 9; ++i) {                // 9 exact iters (6912 = 9*768)
        int idx = i * TPB + tid;
        int t = idx / 48, c4 = idx % 48;
        int wi = t / 9, q = t - 9 * wi;
        long grow = rb0 + wi * 3 + (q / 3) * 288 + (q % 3);
        float4 xv = ((const float4*)x)[grow * 48 + c4];
        union { f16 h[4]; ushort4 u; } tmp;
        tmp.h[0] = (f16)xv.x; tmp.h[1] = (f16)xv.y; tmp.h[2] = (f16)xv.z; tmp.h[3] = (f16)xv.w;
        *(ushort4*)&Xh[t * XS + c4 * 4] = tmp.u;
    }
    {
        int4 z = {0, 0, 0, 0};
        for (int i2 = tid; i2 < (32 * VS * 2) / 16; i2 += TPB) ((int4*)Vt2)[i2] = z;
    }

    f32x4 pacc[9];
    #pragma unroll
    for (int a = 0; a < 9; ++a) pacc[a] = (f32x4){0.f, 0.f, 0.f, 0.f};

    __syncthreads();   // P: Xh, Vt2-zero, Wh(0) ready (vmcnt drained)

    for (int h = 0; h < 6; ++h) {
        // ---- phase A: QKV GEMM (A = W channels from Wh, B = X tokens from Xh) ----
        f32x4 qacc[2][3];
        #pragma unroll
        for (int c = 0; c < 2; ++c)
            #pragma unroll
            for (int t = 0; t < 3; ++t)
                qacc[c][t] = (f32x4){0.f, 0.f, 0.f, 0.f};
        #pragma unroll
        for (int kk = 0; kk < 6; ++kk) {
            f16x8 af[2];
            af[0] = *(const f16x8*)&Wh[(16 * ci        + l15) * WSS + kk * 32 + lg * 8];
            af[1] = *(const f16x8*)&Wh[(16 * (ci + 3)  + l15) * WSS + kk * 32 + lg * 8];
            #pragma unroll
            for (int t = 0; t < 3; ++t) {
                int tt = tg + 4 * t;
                if (tt < 9) {
                    f16x8 bf = *(const f16x8*)&Xh[(16 * tt + l15) * XS + kk * 32 + lg * 8];
                    qacc[0][t] = __builtin_amdgcn_mfma_f32_16x16x32_f16(af[0], bf, qacc[0][t], 0, 0, 0);
                    qacc[1][t] = __builtin_amdgcn_mfma_f32_16x16x32_f16(af[1], bf, qacc[1][t], 0, 0, 0);
                }
            }
        }
        // scatter: lane holds channels (ct*16 + 4lg..+3) of token (16*tt + l15)
        #pragma unroll
        for (int c = 0; c < 2; ++c) {
            const int ct = ci + 3 * c;            // 0..5 wave-uniform
            #pragma unroll
            for (int t = 0; t < 3; ++t) {
                int tt = tg + 4 * t;
                if (tt < 9) {
                    const int token = 16 * tt + l15;
                    f16x4 ph;
                    ph[0] = (f16)qacc[c][t][0]; ph[1] = (f16)qacc[c][t][1];
                    ph[2] = (f16)qacc[c][t][2]; ph[3] = (f16)qacc[c][t][3];
                    if (ct < 2) {
                        *(f16x4*)&Qh[token * QS + ct * 16 + 4 * lg] = ph;
                    } else if (ct < 4) {
                        *(f16x4*)&Kh[token * QS + (ct - 2) * 16 + 4 * lg] = ph;
                    } else {
                        const int d0 = (ct - 4) * 16 + 4 * lg;
                        int wi = token / 9, qq = token - 9 * wi;
                        #pragma unroll
                        for (int r = 0; r < 4; ++r)
                            Vt2[(d0 + r) * VS + 16 * wi + qq] = ph[r];
                    }
                }
            }
        }
        __syncthreads();   // B: Q/K/V ready; Wh reads done

        // ---- phase B: DMA Wh(h+1) + Wp(h) || attention ----
        if (h < 5) {
            for (int l = tid; l < 2400; l += TPB)
                gload16(wsWq + (h + 1) * WSQ_HALVES_PER_HEAD + l * 8, (char*)Wh + l * 16);
        }
        for (int l = tid; l < 960; l += TPB)      // 15360 B = 960 x 16B
            gload16(wsWp + h * WSP_HALVES_PER_HEAD + l * 8, (char*)Wp + l * 16);

        for (int wi = w; wi < NWIN; wi += 12) {
            int krow = 9 * wi + l15;
            krow = krow > 143 ? 143 : krow;        // clamp pad lanes (results discarded)
            f16x8 ak = *(const f16x8*)&Kh[krow * QS + lg * 8];
            f16x8 aq = *(const f16x8*)&Qh[krow * QS + lg * 8];
            f32x4 s = (f32x4){0.f, 0.f, 0.f, 0.f};
            s = __builtin_amdgcn_mfma_f32_16x16x32_f16(ak, aq, s, 0, 0, 0);
            // lane holds S[k = 4lg+r][q = l15]
            float lgt[4];
            float mx = -1e30f;
            #pragma unroll
            for (int r = 0; r < 4; ++r) {
                int kx = 4 * lg + r;
                lgt[r] = (kx < 9) ? s[r] * 0.17677669529663687f : -1e30f;
                mx = fmaxf(mx, lgt[r]);
            }
            mx = fmaxf(mx, __shfl_xor(mx, 16));
            mx = fmaxf(mx, __shfl_xor(mx, 32));
            float e[4], sum = 0.f;
            #pragma unroll
            for (int r = 0; r < 4; ++r) {
                int kx = 4 * lg + r;
                e[r] = (kx < 9) ? __expf(lgt[r] - mx) : 0.f;
                sum += e[r];
            }
            sum += __shfl_xor(sum, 16);
            sum += __shfl_xor(sum, 32);
            float inv = 1.0f / sum;
            f16x4 p;
            p[0] = (f16)(e[0] * inv); p[1] = (f16)(e[1] * inv);
            p[2] = (f16)(e[2] * inv); p[3] = (f16)(e[3] * inv);
            // p IS the B-frag of 16x16x16: B[row=q=l15][k=4lg..+3]
            #pragma unroll
            for (int dt = 0; dt < 2; ++dt) {
                f16x4 av = *(const f16x4*)&Vt2[(dt * 16 + l15) * VS + 16 * wi + 4 * lg];
                f32x4 o = (f32x4){0.f, 0.f, 0.f, 0.f};
                o = __builtin_amdgcn_mfma_f32_16x16x16f16(av, p, o, 0, 0, 0);
                // D: row(4lg+r) = d-in-tile, col(l15) = q
                if (l15 < 9) {
                    f16x4 oh;
                    oh[0] = (f16)o[0]; oh[1] = (f16)o[1]; oh[2] = (f16)o[2]; oh[3] = (f16)o[3];
                    *(f16x4*)&AOh[(9 * wi + l15) * QS + dt * 16 + 4 * lg] = oh;
                }
            }
        }
        __syncthreads();   // C: AOh + Wp + Wh(h+1) ready (vmcnt drained)

        // ---- phase A-tail: proj partial — wave w owns output N-tile w ----
        {
            f16x8 bw = *(const f16x8*)&Wp[(16 * w + l15) * QS + lg * 8];
            #pragma unroll
            for (int a = 0; a < 9; ++a) {
                f16x8 aof = *(const f16x8*)&AOh[(16 * a + l15) * QS + lg * 8];
                pacc[a] = __builtin_amdgcn_mfma_f32_16x16x32_f16(aof, bw, pacc[a], 0, 0, 0);
            }
        }
        // no trailing barrier: next head's barrier B fences AOh/Wp rewrites
    }

    // ---- epilogue: pacc + bias -> out (D row = token, D col = channel 16w+l15) ----
    const float bv = bproj[16 * w + l15];
    #pragma unroll
    for (int a = 0; a < 9; ++a) {
        #pragma unroll
        for (int r = 0; r < 4; ++r) {
            int t = 16 * a + lg * 4 + r;
            int wi = t / 9, q = t - 9 * wi;
            long grow = rb0 + wi * 3 + (q / 3) * 288 + (q % 3);
            out[grow * 192 + 16 * w + l15] = pacc[a][r] + bv;
        }
    }
}

// ---- fallback: R8 kernel verbatim (used if ws_size is too small) ----
__global__ __launch_bounds__(TPBF) void lsa_mfma7(
    const float* __restrict__ x, const float* __restrict__ Wqkv,
    const float* __restrict__ Wproj, const float* __restrict__ bproj,
    float* __restrict__ out)
{
    __shared__ f16 Xh[144 * XS];
    __shared__ f16 Wh[96 * WSS];
    __shared__ f16 Qh[144 * QS];
    __shared__ f16 Kh[144 * QS];
    __shared__ f16 Vt2[32 * VS];
    __shared__ f16 AOh[144 * QS];
    __shared__ f16 Wp[192 * QS];

    const int tid  = threadIdx.x;
    const int lane = tid & 63;
    const int w    = tid >> 6;
    const int ci   = w / 3;
    const int ti   = w % 3;
    const int l15  = lane & 15;
    const int lg   = lane >> 4;

    const int  bb    = blockIdx.x / 768;
    const int  gbase = (blockIdx.x % 768) * NWIN;
    const long rb0   = (long)bb * 110592 + (long)(gbase / 96) * 864 + (long)(gbase % 96) * 3;

    const float4* Wq4 = (const float4*)Wqkv;
    const float4* Wp4 = (const float4*)Wproj;

    for (int idx = tid; idx < 144 * 48; idx += TPBF) {
        int t = idx / 48, c4 = idx % 48;
        int wi = t / 9, q = t - 9 * wi;
        long grow = rb0 + wi * 3 + (q / 3) * 288 + (q % 3);
        float4 xv = ((const float4*)x)[grow * 48 + c4];
        union { f16 h[4]; ushort4 u; } tmp;
        tmp.h[0] = (f16)xv.x; tmp.h[1] = (f16)xv.y; tmp.h[2] = (f16)xv.z; tmp.h[3] = (f16)xv.w;
        *(ushort4*)&Xh[t * XS + c4 * 4] = tmp.u;
    }
    {
        int4 z = {0, 0, 0, 0};
        for (int i2 = tid; i2 < (32 * VS * 2) / 16; i2 += TPBF) ((int4*)Vt2)[i2] = z;
    }
    #pragma unroll
    for (int i = 0; i < 8; ++i) {
        int l = i * TPBF + tid;
        int r = l / 48, c4 = l % 48;
        float4 wv = Wq4[((r >> 5) * 192 + (r & 31)) * 48 + c4];
        union { f16 h4[4]; ushort4 u; } t;
        t.h4[0] = (f16)wv.x; t.h4[1] = (f16)wv.y; t.h4[2] = (f16)wv.z; t.h4[3] = (f16)wv.w;
        *(ushort4*)&Wh[r * WSS + c4 * 4] = t.u;
    }

    f32x4 pacc[3][4];
    #pragma unroll
    for (int a = 0; a < 3; ++a)
        #pragma unroll
        for (int bq = 0; bq < 4; ++bq)
            pacc[a][bq] = (f32x4){0.f, 0.f, 0.f, 0.f};

    __syncthreads();

    for (int h = 0; h < 6; ++h) {
        f32x4 qacc[2][3];
        #pragma unroll
        for (int c = 0; c < 2; ++c)
            #pragma unroll
            for (int t = 0; t < 3; ++t)
                qacc[c][t] = (f32x4){0.f, 0.f, 0.f, 0.f};
        #pragma unroll
        for (int kk = 0; kk < 6; ++kk) {
            f16x8 af[2], bf[3];
            #pragma unroll
            for (int c = 0; c < 2; ++c)
                af[c] = *(const f16x8*)&Wh[(16 * (ci + 3 * c) + l15) * WSS + kk * 32 + lg * 8];
            #pragma unroll
            for (int t = 0; t < 3; ++t)
                bf[t] = *(const f16x8*)&Xh[(16 * (ti + 3 * t) + l15) * XS + kk * 32 + lg * 8];
            #pragma unroll
            for (int c = 0; c < 2; ++c)
                #pragma unroll
                for (int t = 0; t < 3; ++t)
                    qacc[c][t] = __builtin_amdgcn_mfma_f32_16x16x32_f16(af[c], bf[t], qacc[c][t], 0, 0, 0);
        }
        #pragma unroll
        for (int c = 0; c < 2; ++c) {
            const int ct = ci + 3 * c;
            #pragma unroll
            for (int t = 0; t < 3; ++t) {
                const int token = 16 * (ti + 3 * t) + l15;
                f16x4 ph;
                ph[0] = (f16)qacc[c][t][0]; ph[1] = (f16)qacc[c][t][1];
                ph[2] = (f16)qacc[c][t][2]; ph[3] = (f16)qacc[c][t][3];
                if (ct < 2) {
                    *(f16x4*)&Qh[token * QS + ct * 16 + 4 * lg] = ph;
                } else if (ct < 4) {
                    *(f16x4*)&Kh[token * QS + (ct - 2) * 16 + 4 * lg] = ph;
                } else {
                    const int d0 = (ct - 4) * 16 + 4 * lg;
                    int wi = token / 9, qq = token - 9 * wi;
                    #pragma unroll
                    for (int r = 0; r < 4; ++r)
                        Vt2[(d0 + r) * VS + 16 * wi + qq] = ph[r];
                }
            }
        }
        __syncthreads();

        float4 wpv[3];
        if (tid < 512) {
            #pragma unroll
            for (int i = 0; i < 3; ++i) {
                int l = i * 512 + tid;
                int r = l / 8, c4 = l % 8;
                wpv[i] = Wp4[r * 48 + h * 8 + c4];
            }
        }
        if (h < 5) {
            #pragma unroll
            for (int i = 0; i < 8; ++i) {
                int l = i * TPBF + tid;
                int r = l / 48, c4 = l % 48;
                float4 wv = Wq4[((r >> 5) * 192 + (h + 1) * 32 + (r & 31)) * 48 + c4];
                union { f16 h4[4]; ushort4 u; } t;
                t.h4[0] = (f16)wv.x; t.h4[1] = (f16)wv.y; t.h4[2] = (f16)wv.z; t.h4[3] = (f16)wv.w;
                *(ushort4*)&Wh[r * WSS + c4 * 4] = t.u;
            }
        }
        for (int wi = w; wi < NWIN; wi += 9) {
            int krow = 9 * wi + l15;
            krow = krow > 143 ? 143 : krow;
            f16x8 ak = *(const f16x8*)&Kh[krow * QS + lg * 8];
            f16x8 aq = *(const f16x8*)&Qh[krow * QS + lg * 8];
            f32x4 s = (f32x4){0.f, 0.f, 0.f, 0.f};
            s = __builtin_amdgcn_mfma_f32_16x16x32_f16(ak, aq, s, 0, 0, 0);
            float lgt[4];
            float mx = -1e30f;
            #pragma unroll
            for (int r = 0; r < 4; ++r) {
                int kx = 4 * lg + r;
                lgt[r] = (kx < 9) ? s[r] * 0.17677669529663687f : -1e30f;
                mx = fmaxf(mx, lgt[r]);
            }
            mx = fmaxf(mx, __shfl_xor(mx, 16));
            mx = fmaxf(mx, __shfl_xor(mx, 32));
            float e[4], sum = 0.f;
            #pragma unroll
            for (int r = 0; r < 4; ++r) {
                int kx = 4 * lg + r;
                e[r] = (kx < 9) ? __expf(lgt[r] - mx) : 0.f;
                sum += e[r];
            }
            sum += __shfl_xor(sum, 16);
            sum += __shfl_xor(sum, 32);
            float inv = 1.0f / sum;
            f16x4 p;
            p[0] = (f16)(e[0] * inv); p[1] = (f16)(e[1] * inv);
            p[2] = (f16)(e[2] * inv); p[3] = (f16)(e[3] * inv);
            #pragma unroll
            for (int dt = 0; dt < 2; ++dt) {
                f16x4 av = *(const f16x4*)&Vt2[(dt * 16 + l15) * VS + 16 * wi + 4 * lg];
                f32x4 o = (f32x4){0.f, 0.f, 0.f, 0.f};
                o = __builtin_amdgcn_mfma_f32_16x16x16f16(av, p, o, 0, 0, 0);
                if (l15 < 9) {
                    f16x4 oh;
                    oh[0] = (f16)o[0]; oh[1] = (f16)o[1]; oh[2] = (f16)o[2]; oh[3] = (f16)o[3];
                    *(f16x4*)&AOh[(9 * wi + l15) * QS + dt * 16 + 4 * lg] = oh;
                }
            }
        }
        if (tid < 512) {
            #pragma unroll
            for (int i = 0; i < 3; ++i) {
                int l = i * 512 + tid;
                int r = l / 8, c4 = l % 8;
                union { f16 h4[4]; ushort4 u; } t;
                t.h4[0] = (f16)wpv[i].x; t.h4[1] = (f16)wpv[i].y;
                t.h4[2] = (f16)wpv[i].z; t.h4[3] = (f16)wpv[i].w;
                *(ushort4*)&Wp[r * QS + c4 * 4] = t.u;
            }
        }
        __syncthreads();

        {
            f16x8 aof[3];
            #pragma unroll
            for (int a = 0; a < 3; ++a)
                aof[a] = *(const f16x8*)&AOh[(16 * (3 * ci + a) + l15) * QS + lg * 8];
            #pragma unroll
            for (int bq = 0; bq < 4; ++bq) {
                f16x8 bw = *(const f16x8*)&Wp[(16 * (4 * ti + bq) + l15) * QS + lg * 8];
                #pragma unroll
                for (int a = 0; a < 3; ++a)
                    pacc[a][bq] = __builtin_amdgcn_mfma_f32_16x16x32_f16(aof[a], bw, pacc[a][bq], 0, 0, 0);
            }
        }
    }

    float bv[4];
    #pragma unroll
    for (int bq = 0; bq < 4; ++bq)
        bv[bq] = bproj[16 * (4 * ti + bq) + l15];
    #pragma unroll
    for (int a = 0; a < 3; ++a) {
        #pragma unroll
        for (int r = 0; r < 4; ++r) {
            int t = 16 * (3 * ci + a) + lg * 4 + r;
            int wi = t / 9, q = t - 9 * wi;
            long grow = rb0 + wi * 3 + (q / 3) * 288 + (q % 3);
            float* dst = out + grow * 192;
            #pragma unroll
            for (int bq = 0; bq < 4; ++bq)
                dst[16 * (4 * ti + bq) + l15] = pacc[a][bq][r] + bv[bq];
        }
    }
}

extern "C" void kernel_launch(void* const* d_in, const int* in_sizes, int n_in,
                              void* d_out, int out_size, void* d_ws, size_t ws_size,
                              hipStream_t stream) {
    const float* x     = (const float*)d_in[0];
    const float* Wqkv  = (const float*)d_in[1];
    const float* Wproj = (const float*)d_in[2];
    const float* bproj = (const float*)d_in[3];
    float* out = (float*)d_out;
    if (ws_size >= (size_t)WS_NEEDED && d_ws != nullptr) {
        f16* wsWq = (f16*)d_ws;
        f16* wsWp = (f16*)((char*)d_ws + 230400);
        conv_w<<<288, 512, 0, stream>>>(Wqkv, Wproj, wsWq, wsWp);
        lsa_mfma14<<<1536, TPB, 0, stream>>>(x, wsWq, wsWp, bproj, out);
    } else {
        lsa_mfma7<<<1536, TPBF, 0, stream>>>(x, Wqkv, Wproj, bproj, out);
    }
}

// Round 19
// 192.292 us; speedup vs baseline: 1.1934x; 1.0297x over previous
//
#include <hip/hip_runtime.h>

typedef _Float16 f16;
typedef _Float16 f16x4 __attribute__((ext_vector_type(4)));
typedef _Float16 f16x8 __attribute__((ext_vector_type(8)));
typedef float f32x4 __attribute__((ext_vector_type(4)));

#define TPB  1024          // 16 waves (4 per SIMD); QKV/proj use waves 0-11, attn all 16
#define TPBF 576           // fallback kernel
#define NWIN 16            // windows per block
#define XS   200           // Xh row stride (halves): 400B = 25x16B
#define WSS  200           // Wh row stride
#define QS   40            // Qh/Kh/AOh/Wp row stride: 80B = 5x16B
#define VS   264           // Vt2 row stride: 528B = 33x16B

// ws layout: wsWq [6][96][200] f16 = 230400 B, then wsWp [6][192][40] f16 = 92160 B
#define WSQ_HALVES_PER_HEAD (96 * 200)     // 19200
#define WSP_HALVES_PER_HEAD (192 * 40)     // 7680
#define WS_NEEDED (230400 + 92160)

__device__ __forceinline__ void gload16(const void* g, void* l) {
    __builtin_amdgcn_global_load_lds(
        (const __attribute__((address_space(1))) unsigned int*)g,
        (__attribute__((address_space(3))) unsigned int*)l, 16, 0, 0);
}

// ---- pre-kernel: convert weights to fp16 in the exact padded LDS image ----
__global__ __launch_bounds__(512) void conv_w(
    const float* __restrict__ Wqkv, const float* __restrict__ Wproj,
    f16* __restrict__ wsWq, f16* __restrict__ wsWp)
{
    int idx = blockIdx.x * 512 + threadIdx.x;   // 288 blocks * 512 = 147456 exact
    if (idx < 110592) {                          // 6*96*192
        int h = idx / (96 * 192), rem = idx % (96 * 192);
        int r = rem / 192, c = rem % 192;
        int grow = (r >> 5) * 192 + h * 32 + (r & 31);
        wsWq[(h * 96 + r) * 200 + c] = (f16)Wqkv[grow * 192 + c];
    } else {
        int j = idx - 110592;                    // 6*192*32
        int h = j / (192 * 32), rem = j % (192 * 32);
        int r = rem / 32, c = rem % 32;
        wsWp[(h * 192 + r) * 40 + c] = (f16)Wproj[r * 192 + h * 32 + c];
    }
}

__global__ __launch_bounds__(TPB) void lsa_mfma17(
    const float* __restrict__ x, const f16* __restrict__ wsWq,
    const f16* __restrict__ wsWp, const float* __restrict__ bproj,
    float* __restrict__ out)
{
    // LDS: 57600 + 38400 + 11520 + 11520 + 16896 + 11520 + 15360 = 162816 B
    __shared__ __attribute__((aligned(16))) f16 Xh[144 * XS];
    __shared__ __attribute__((aligned(16))) f16 Wh[96 * WSS];
    __shared__ __attribute__((aligned(16))) f16 Qh[144 * QS];
    __shared__ __attribute__((aligned(16))) f16 Kh[144 * QS];
    __shared__ __attribute__((aligned(16))) f16 Vt2[32 * VS];
    __shared__ __attribute__((aligned(16))) f16 AOh[144 * QS];
    __shared__ __attribute__((aligned(16))) f16 Wp[192 * QS];

    const int tid  = threadIdx.x;
    const int lane = tid & 63;
    const int w    = tid >> 6;      // wave 0..15
    const int ci   = w % 3;         // QKV ct-pair {ci, ci+3} (waves 0..11)
    const int tg   = w / 3;         // QKV token-group: tiles {tg, tg+4, tg+8(<9)}
    const int l15  = lane & 15;
    const int lg   = lane >> 4;     // 0..3

    // ---- geometry: 16 windows per block ----
    const int  bb    = blockIdx.x / 768;
    const int  gbase = (blockIdx.x % 768) * NWIN;
    const long rb0   = (long)bb * 110592 + (long)(gbase / 96) * 864 + (long)(gbase % 96) * 3;

    // ---- prologue: DMA Wh(0); X -> LDS fp16; zero Vt2 ----
    for (int l = tid; l < 2400; l += TPB)        // 38400 B = 2400 x 16B
        gload16(wsWq + l * 8, (char*)Wh + l * 16);
    for (int idx = tid; idx < 144 * 48; idx += TPB) {
        int t = idx / 48, c4 = idx % 48;
        int wi = t / 9, q = t - 9 * wi;
        long grow = rb0 + wi * 3 + (q / 3) * 288 + (q % 3);
        float4 xv = ((const float4*)x)[grow * 48 + c4];
        union { f16 h[4]; ushort4 u; } tmp;
        tmp.h[0] = (f16)xv.x; tmp.h[1] = (f16)xv.y; tmp.h[2] = (f16)xv.z; tmp.h[3] = (f16)xv.w;
        *(ushort4*)&Xh[t * XS + c4 * 4] = tmp.u;
    }
    {
        int4 z = {0, 0, 0, 0};
        for (int i2 = tid; i2 < (32 * VS * 2) / 16; i2 += TPB) ((int4*)Vt2)[i2] = z;
    }

    f32x4 pacc[9];
    #pragma unroll
    for (int a = 0; a < 9; ++a) pacc[a] = (f32x4){0.f, 0.f, 0.f, 0.f};

    __syncthreads();   // P: Xh, Vt2-zero, Wh(0) ready (vmcnt drained)

    for (int h = 0; h < 6; ++h) {
        // ---- phase A: QKV GEMM on waves 0..11 (A = W from Wh, B = X from Xh) ----
        if (w < 12) {
            f32x4 qacc[2][3];
            #pragma unroll
            for (int c = 0; c < 2; ++c)
                #pragma unroll
                for (int t = 0; t < 3; ++t)
                    qacc[c][t] = (f32x4){0.f, 0.f, 0.f, 0.f};
            #pragma unroll
            for (int kk = 0; kk < 6; ++kk) {
                f16x8 af[2];
                af[0] = *(const f16x8*)&Wh[(16 * ci        + l15) * WSS + kk * 32 + lg * 8];
                af[1] = *(const f16x8*)&Wh[(16 * (ci + 3)  + l15) * WSS + kk * 32 + lg * 8];
                #pragma unroll
                for (int t = 0; t < 3; ++t) {
                    int tt = tg + 4 * t;
                    if (tt < 9) {
                        f16x8 bf = *(const f16x8*)&Xh[(16 * tt + l15) * XS + kk * 32 + lg * 8];
                        qacc[0][t] = __builtin_amdgcn_mfma_f32_16x16x32_f16(af[0], bf, qacc[0][t], 0, 0, 0);
                        qacc[1][t] = __builtin_amdgcn_mfma_f32_16x16x32_f16(af[1], bf, qacc[1][t], 0, 0, 0);
                    }
                }
            }
            // scatter: lane holds channels (ct*16 + 4lg..+3) of token (16*tt + l15)
            #pragma unroll
            for (int c = 0; c < 2; ++c) {
                const int ct = ci + 3 * c;            // 0..5 wave-uniform
                #pragma unroll
                for (int t = 0; t < 3; ++t) {
                    int tt = tg + 4 * t;
                    if (tt < 9) {
                        const int token = 16 * tt + l15;
                        f16x4 ph;
                        ph[0] = (f16)qacc[c][t][0]; ph[1] = (f16)qacc[c][t][1];
                        ph[2] = (f16)qacc[c][t][2]; ph[3] = (f16)qacc[c][t][3];
                        if (ct < 2) {
                            *(f16x4*)&Qh[token * QS + ct * 16 + 4 * lg] = ph;
                        } else if (ct < 4) {
                            *(f16x4*)&Kh[token * QS + (ct - 2) * 16 + 4 * lg] = ph;
                        } else {
                            const int d0 = (ct - 4) * 16 + 4 * lg;
                            int wi = token / 9, qq = token - 9 * wi;
                            #pragma unroll
                            for (int r = 0; r < 4; ++r)
                                Vt2[(d0 + r) * VS + 16 * wi + qq] = ph[r];
                        }
                    }
                }
            }
        }
        __syncthreads();   // B: Q/K/V ready; Wh reads done

        // ---- phase B: DMA Wh(h+1) + Wp(h) || attention (1 window per wave) ----
        if (h < 5) {
            for (int l = tid; l < 2400; l += TPB)
                gload16(wsWq + (h + 1) * WSQ_HALVES_PER_HEAD + l * 8, (char*)Wh + l * 16);
        }
        for (int l = tid; l < 960; l += TPB)      // 15360 B = 960 x 16B
            gload16(wsWp + h * WSP_HALVES_PER_HEAD + l * 8, (char*)Wp + l * 16);

        {
            const int wi = w;                      // 16 waves <-> 16 windows, 1:1
            int krow = 9 * wi + l15;
            krow = krow > 143 ? 143 : krow;        // clamp pad lanes (results discarded)
            f16x8 ak = *(const f16x8*)&Kh[krow * QS + lg * 8];
            f16x8 aq = *(const f16x8*)&Qh[krow * QS + lg * 8];
            f32x4 s = (f32x4){0.f, 0.f, 0.f, 0.f};
            s = __builtin_amdgcn_mfma_f32_16x16x32_f16(ak, aq, s, 0, 0, 0);
            // lane holds S[k = 4lg+r][q = l15]
            float lgt[4];
            float mx = -1e30f;
            #pragma unroll
            for (int r = 0; r < 4; ++r) {
                int kx = 4 * lg + r;
                lgt[r] = (kx < 9) ? s[r] * 0.17677669529663687f : -1e30f;
                mx = fmaxf(mx, lgt[r]);
            }
            mx = fmaxf(mx, __shfl_xor(mx, 16));
            mx = fmaxf(mx, __shfl_xor(mx, 32));
            float e[4], sum = 0.f;
            #pragma unroll
            for (int r = 0; r < 4; ++r) {
                int kx = 4 * lg + r;
                e[r] = (kx < 9) ? __expf(lgt[r] - mx) : 0.f;
                sum += e[r];
            }
            sum += __shfl_xor(sum, 16);
            sum += __shfl_xor(sum, 32);
            float inv = 1.0f / sum;
            f16x4 p;
            p[0] = (f16)(e[0] * inv); p[1] = (f16)(e[1] * inv);
            p[2] = (f16)(e[2] * inv); p[3] = (f16)(e[3] * inv);
            // p IS the B-frag of 16x16x16: B[row=q=l15][k=4lg..+3]
            #pragma unroll
            for (int dt = 0; dt < 2; ++dt) {
                f16x4 av = *(const f16x4*)&Vt2[(dt * 16 + l15) * VS + 16 * wi + 4 * lg];
                f32x4 o = (f32x4){0.f, 0.f, 0.f, 0.f};
                o = __builtin_amdgcn_mfma_f32_16x16x16f16(av, p, o, 0, 0, 0);
                // D: row(4lg+r) = d-in-tile, col(l15) = q
                if (l15 < 9) {
                    f16x4 oh;
                    oh[0] = (f16)o[0]; oh[1] = (f16)o[1]; oh[2] = (f16)o[2]; oh[3] = (f16)o[3];
                    *(f16x4*)&AOh[(9 * wi + l15) * QS + dt * 16 + 4 * lg] = oh;
                }
            }
        }
        __syncthreads();   // C: AOh + Wp + Wh(h+1) ready (vmcnt drained)

        // ---- phase A-tail: proj partial — waves 0..11 own output N-tiles ----
        if (w < 12) {
            f16x8 bw = *(const f16x8*)&Wp[(16 * w + l15) * QS + lg * 8];
            #pragma unroll
            for (int a = 0; a < 9; ++a) {
                f16x8 aof = *(const f16x8*)&AOh[(16 * a + l15) * QS + lg * 8];
                pacc[a] = __builtin_amdgcn_mfma_f32_16x16x32_f16(aof, bw, pacc[a], 0, 0, 0);
            }
        }
        // no trailing barrier: next head's barrier B fences AOh/Wp rewrites
    }

    // ---- epilogue: pacc + bias -> out (D row = token, D col = channel 16w+l15) ----
    if (w < 12) {
        const float bv = bproj[16 * w + l15];
        #pragma unroll
        for (int a = 0; a < 9; ++a) {
            #pragma unroll
            for (int r = 0; r < 4; ++r) {
                int t = 16 * a + lg * 4 + r;
                int wi = t / 9, q = t - 9 * wi;
                long grow = rb0 + wi * 3 + (q / 3) * 288 + (q % 3);
                out[grow * 192 + 16 * w + l15] = pacc[a][r] + bv;
            }
        }
    }
}

// ---- fallback: R8 kernel verbatim (used if ws_size is too small) ----
__global__ __launch_bounds__(TPBF) void lsa_mfma7(
    const float* __restrict__ x, const float* __restrict__ Wqkv,
    const float* __restrict__ Wproj, const float* __restrict__ bproj,
    float* __restrict__ out)
{
    __shared__ f16 Xh[144 * XS];
    __shared__ f16 Wh[96 * WSS];
    __shared__ f16 Qh[144 * QS];
    __shared__ f16 Kh[144 * QS];
    __shared__ f16 Vt2[32 * VS];
    __shared__ f16 AOh[144 * QS];
    __shared__ f16 Wp[192 * QS];

    const int tid  = threadIdx.x;
    const int lane = tid & 63;
    const int w    = tid >> 6;
    const int ci   = w / 3;
    const int ti   = w % 3;
    const int l15  = lane & 15;
    const int lg   = lane >> 4;

    const int  bb    = blockIdx.x / 768;
    const int  gbase = (blockIdx.x % 768) * NWIN;
    const long rb0   = (long)bb * 110592 + (long)(gbase / 96) * 864 + (long)(gbase % 96) * 3;

    const float4* Wq4 = (const float4*)Wqkv;
    const float4* Wp4 = (const float4*)Wproj;

    for (int idx = tid; idx < 144 * 48; idx += TPBF) {
        int t = idx / 48, c4 = idx % 48;
        int wi = t / 9, q = t - 9 * wi;
        long grow = rb0 + wi * 3 + (q / 3) * 288 + (q % 3);
        float4 xv = ((const float4*)x)[grow * 48 + c4];
        union { f16 h[4]; ushort4 u; } tmp;
        tmp.h[0] = (f16)xv.x; tmp.h[1] = (f16)xv.y; tmp.h[2] = (f16)xv.z; tmp.h[3] = (f16)xv.w;
        *(ushort4*)&Xh[t * XS + c4 * 4] = tmp.u;
    }
    {
        int4 z = {0, 0, 0, 0};
        for (int i2 = tid; i2 < (32 * VS * 2) / 16; i2 += TPBF) ((int4*)Vt2)[i2] = z;
    }
    #pragma unroll
    for (int i = 0; i < 8; ++i) {
        int l = i * TPBF + tid;
        int r = l / 48, c4 = l % 48;
        float4 wv = Wq4[((r >> 5) * 192 + (r & 31)) * 48 + c4];
        union { f16 h4[4]; ushort4 u; } t;
        t.h4[0] = (f16)wv.x; t.h4[1] = (f16)wv.y; t.h4[2] = (f16)wv.z; t.h4[3] = (f16)wv.w;
        *(ushort4*)&Wh[r * WSS + c4 * 4] = t.u;
    }

    f32x4 pacc[3][4];
    #pragma unroll
    for (int a = 0; a < 3; ++a)
        #pragma unroll
        for (int bq = 0; bq < 4; ++bq)
            pacc[a][bq] = (f32x4){0.f, 0.f, 0.f, 0.f};

    __syncthreads();

    for (int h = 0; h < 6; ++h) {
        f32x4 qacc[2][3];
        #pragma unroll
        for (int c = 0; c < 2; ++c)
            #pragma unroll
            for (int t = 0; t < 3; ++t)
                qacc[c][t] = (f32x4){0.f, 0.f, 0.f, 0.f};
        #pragma unroll
        for (int kk = 0; kk < 6; ++kk) {
            f16x8 af[2], bf[3];
            #pragma unroll
            for (int c = 0; c < 2; ++c)
                af[c] = *(const f16x8*)&Wh[(16 * (ci + 3 * c) + l15) * WSS + kk * 32 + lg * 8];
            #pragma unroll
            for (int t = 0; t < 3; ++t)
                bf[t] = *(const f16x8*)&Xh[(16 * (ti + 3 * t) + l15) * XS + kk * 32 + lg * 8];
            #pragma unroll
            for (int c = 0; c < 2; ++c)
                #pragma unroll
                for (int t = 0; t < 3; ++t)
                    qacc[c][t] = __builtin_amdgcn_mfma_f32_16x16x32_f16(af[c], bf[t], qacc[c][t], 0, 0, 0);
        }
        #pragma unroll
        for (int c = 0; c < 2; ++c) {
            const int ct = ci + 3 * c;
            #pragma unroll
            for (int t = 0; t < 3; ++t) {
                const int token = 16 * (ti + 3 * t) + l15;
                f16x4 ph;
                ph[0] = (f16)qacc[c][t][0]; ph[1] = (f16)qacc[c][t][1];
                ph[2] = (f16)qacc[c][t][2]; ph[3] = (f16)qacc[c][t][3];
                if (ct < 2) {
                    *(f16x4*)&Qh[token * QS + ct * 16 + 4 * lg] = ph;
                } else if (ct < 4) {
                    *(f16x4*)&Kh[token * QS + (ct - 2) * 16 + 4 * lg] = ph;
                } else {
                    const int d0 = (ct - 4) * 16 + 4 * lg;
                    int wi = token / 9, qq = token - 9 * wi;
                    #pragma unroll
                    for (int r = 0; r < 4; ++r)
                        Vt2[(d0 + r) * VS + 16 * wi + qq] = ph[r];
                }
            }
        }
        __syncthreads();

        float4 wpv[3];
        if (tid < 512) {
            #pragma unroll
            for (int i = 0; i < 3; ++i) {
                int l = i * 512 + tid;
                int r = l / 8, c4 = l % 8;
                wpv[i] = Wp4[r * 48 + h * 8 + c4];
            }
        }
        if (h < 5) {
            #pragma unroll
            for (int i = 0; i < 8; ++i) {
                int l = i * TPBF + tid;
                int r = l / 48, c4 = l % 48;
                float4 wv = Wq4[((r >> 5) * 192 + (h + 1) * 32 + (r & 31)) * 48 + c4];
                union { f16 h4[4]; ushort4 u; } t;
                t.h4[0] = (f16)wv.x; t.h4[1] = (f16)wv.y; t.h4[2] = (f16)wv.z; t.h4[3] = (f16)wv.w;
                *(ushort4*)&Wh[r * WSS + c4 * 4] = t.u;
            }
        }
        for (int wi = w; wi < NWIN; wi += 9) {
            int krow = 9 * wi + l15;
            krow = krow > 143 ? 143 : krow;
            f16x8 ak = *(const f16x8*)&Kh[krow * QS + lg * 8];
            f16x8 aq = *(const f16x8*)&Qh[krow * QS + lg * 8];
            f32x4 s = (f32x4){0.f, 0.f, 0.f, 0.f};
            s = __builtin_amdgcn_mfma_f32_16x16x32_f16(ak, aq, s, 0, 0, 0);
            float lgt[4];
            float mx = -1e30f;
            #pragma unroll
            for (int r = 0; r < 4; ++r) {
                int kx = 4 * lg + r;
                lgt[r] = (kx < 9) ? s[r] * 0.17677669529663687f : -1e30f;
                mx = fmaxf(mx, lgt[r]);
            }
            mx = fmaxf(mx, __shfl_xor(mx, 16));
            mx = fmaxf(mx, __shfl_xor(mx, 32));
            float e[4], sum = 0.f;
            #pragma unroll
            for (int r = 0; r < 4; ++r) {
                int kx = 4 * lg + r;
                e[r] = (kx < 9) ? __expf(lgt[r] - mx) : 0.f;
                sum += e[r];
            }
            sum += __shfl_xor(sum, 16);
            sum += __shfl_xor(sum, 32);
            float inv = 1.0f / sum;
            f16x4 p;
            p[0] = (f16)(e[0] * inv); p[1] = (f16)(e[1] * inv);
            p[2] = (f16)(e[2] * inv); p[3] = (f16)(e[3] * inv);
            #pragma unroll
            for (int dt = 0; dt < 2; ++dt) {
                f16x4 av = *(const f16x4*)&Vt2[(dt * 16 + l15) * VS + 16 * wi + 4 * lg];
                f32x4 o = (f32x4){0.f, 0.f, 0.f, 0.f};
                o = __builtin_amdgcn_mfma_f32_16x16x16f16(av, p, o, 0, 0, 0);
                if (l15 < 9) {
                    f16x4 oh;
                    oh[0] = (f16)o[0]; oh[1] = (f16)o[1]; oh[2] = (f16)o[2]; oh[3] = (f16)o[3];
                    *(f16x4*)&AOh[(9 * wi + l15) * QS + dt * 16 + 4 * lg] = oh;
                }
            }
        }
        if (tid < 512) {
            #pragma unroll
            for (int i = 0; i < 3; ++i) {
                int l = i * 512 + tid;
                int r = l / 8, c4 = l % 8;
                union { f16 h4[4]; ushort4 u; } t;
                t.h4[0] = (f16)wpv[i].x; t.h4[1] = (f16)wpv[i].y;
                t.h4[2] = (f16)wpv[i].z; t.h4[3] = (f16)wpv[i].w;
                *(ushort4*)&Wp[r * QS + c4 * 4] = t.u;
            }
        }
        __syncthreads();

        {
            f16x8 aof[3];
            #pragma unroll
            for (int a = 0; a < 3; ++a)
                aof[a] = *(const f16x8*)&AOh[(16 * (3 * ci + a) + l15) * QS + lg * 8];
            #pragma unroll
            for (int bq = 0; bq < 4; ++bq) {
                f16x8 bw = *(const f16x8*)&Wp[(16 * (4 * ti + bq) + l15) * QS + lg * 8];
                #pragma unroll
                for (int a = 0; a < 3; ++a)
                    pacc[a][bq] = __builtin_amdgcn_mfma_f32_16x16x32_f16(aof[a], bw, pacc[a][bq], 0, 0, 0);
            }
        }
    }

    float bv[4];
    #pragma unroll
    for (int bq = 0; bq < 4; ++bq)
        bv[bq] = bproj[16 * (4 * ti + bq) + l15];
    #pragma unroll
    for (int a = 0; a < 3; ++a) {
        #pragma unroll
        for (int r = 0; r < 4; ++r) {
            int t = 16 * (3 * ci + a) + lg * 4 + r;
            int wi = t / 9, q = t - 9 * wi;
            long grow = rb0 + wi * 3 + (q / 3) * 288 + (q % 3);
            float* dst = out + grow * 192;
            #pragma unroll
            for (int bq = 0; bq < 4; ++bq)
                dst[16 * (4 * ti + bq) + l15] = pacc[a][bq][r] + bv[bq];
        }
    }
}

extern "C" void kernel_launch(void* const* d_in, const int* in_sizes, int n_in,
                              void* d_out, int out_size, void* d_ws, size_t ws_size,
                              hipStream_t stream) {
    const float* x     = (const float*)d_in[0];
    const float* Wqkv  = (const float*)d_in[1];
    const float* Wproj = (const float*)d_in[2];
    const float* bproj = (const float*)d_in[3];
    float* out = (float*)d_out;
    if (ws_size >= (size_t)WS_NEEDED && d_ws != nullptr) {
        f16* wsWq = (f16*)d_ws;
        f16* wsWp = (f16*)((char*)d_ws + 230400);
        conv_w<<<288, 512, 0, stream>>>(Wqkv, Wproj, wsWq, wsWp);
        lsa_mfma17<<<1536, TPB, 0, stream>>>(x, wsWq, wsWp, bproj, out);
    } else {
        lsa_mfma7<<<1536, TPBF, 0, stream>>>(x, Wqkv, Wproj, bproj, out);
    }
}